// Round 5
// baseline (298.668 us; speedup 1.0000x reference)
//
#include <hip/hip_runtime.h>

// LJ pair-energy, round 5: 2-D bucket sort -> LDS-served gathers.
// R3's 90us is the MSHR roofline for random global gathers (16.8M reqs x
// ~210cy / ~64 MSHR/CU). Restructure: bin pairs by (i>>12, j>>12) into
// 64x64=4096 buckets; compute kernel stages both 4096-particle slices in
// 96KB LDS and serves all position reads from LDS.
// Fallback to the R3 kernel if ws/LDS requirements aren't met.

typedef int vint4 __attribute__((ext_vector_type(4)));

#define NB    4096      // 64 x 64 buckets
#define SLICE 4096      // particles per slice
#define SB    256       // sort-phase blocks
#define ST    1024      // sort-phase threads

// ---------- Pass A: per-bucket histogram (LDS-aggregated) ----------
__global__ __launch_bounds__(ST) void hist_kernel(
    const vint4* __restrict__ ii, const vint4* __restrict__ jj,
    unsigned* __restrict__ count, int n4)
{
    __shared__ unsigned h[NB];
    for (int b = threadIdx.x; b < NB; b += ST) h[b] = 0;
    __syncthreads();
    const int stride = gridDim.x * ST;
    for (int s = blockIdx.x * ST + threadIdx.x; s < n4; s += stride) {
        vint4 a = __builtin_nontemporal_load(ii + s);
        vint4 b = __builtin_nontemporal_load(jj + s);
        const int ia[4] = {a.x, a.y, a.z, a.w};
        const int ja[4] = {b.x, b.y, b.z, b.w};
#pragma unroll
        for (int k = 0; k < 4; ++k) {
            int bk = ((ia[k] >> 12) << 6) | (ja[k] >> 12);
            atomicAdd(&h[bk], 1u);
        }
    }
    __syncthreads();
    for (int b = threadIdx.x; b < NB; b += ST) {
        unsigned v = h[b];
        if (v) atomicAdd(&count[b], v);
    }
}

// ---------- Pass B: exclusive scan of 4096 counts ----------
__global__ __launch_bounds__(ST) void scan_kernel(
    const unsigned* __restrict__ count, unsigned* __restrict__ start,
    unsigned* __restrict__ cursor)
{
    __shared__ unsigned s[ST];
    const int t = threadIdx.x;
    unsigned c0 = count[4*t], c1 = count[4*t+1], c2 = count[4*t+2], c3 = count[4*t+3];
    unsigned tot = c0 + c1 + c2 + c3;
    s[t] = tot;
    __syncthreads();
    for (int off = 1; off < ST; off <<= 1) {
        unsigned v = (t >= off) ? s[t - off] : 0u;
        __syncthreads();
        s[t] += v;
        __syncthreads();
    }
    unsigned base = s[t] - tot;            // exclusive
    unsigned p0 = base, p1 = p0 + c0, p2 = p1 + c1, p3 = p2 + c2;
    start[4*t] = p0; start[4*t+1] = p1; start[4*t+2] = p2; start[4*t+3] = p3;
    cursor[4*t] = p0; cursor[4*t+1] = p1; cursor[4*t+2] = p2; cursor[4*t+3] = p3;
    if (t == ST - 1) start[NB] = base + tot;
}

// ---------- Pass C: scatter packed pairs into bucket order ----------
__global__ __launch_bounds__(ST) void scatter_kernel(
    const vint4* __restrict__ ii, const vint4* __restrict__ jj,
    unsigned* __restrict__ cursor, unsigned* __restrict__ sorted, int n4)
{
    __shared__ unsigned h[NB];
    for (int b = threadIdx.x; b < NB; b += ST) h[b] = 0;
    __syncthreads();
    const int stride = gridDim.x * ST;
    // phase 1: block-local histogram
    for (int s = blockIdx.x * ST + threadIdx.x; s < n4; s += stride) {
        vint4 a = ii[s];
        vint4 b = jj[s];
        const int ia[4] = {a.x, a.y, a.z, a.w};
        const int ja[4] = {b.x, b.y, b.z, b.w};
#pragma unroll
        for (int k = 0; k < 4; ++k) {
            int bk = ((ia[k] >> 12) << 6) | (ja[k] >> 12);
            atomicAdd(&h[bk], 1u);
        }
    }
    __syncthreads();
    // phase 2: reserve contiguous ranges; h[b] becomes this block's cursor
    for (int b = threadIdx.x; b < NB; b += ST) {
        unsigned cnt = h[b];
        if (cnt) h[b] = atomicAdd(&cursor[b], cnt);
    }
    __syncthreads();
    // phase 3: re-read pairs, write packed local indices to exact slots
    for (int s = blockIdx.x * ST + threadIdx.x; s < n4; s += stride) {
        vint4 a = ii[s];
        vint4 b = jj[s];
        const int ia[4] = {a.x, a.y, a.z, a.w};
        const int ja[4] = {b.x, b.y, b.z, b.w};
#pragma unroll
        for (int k = 0; k < 4; ++k) {
            int bk = ((ia[k] >> 12) << 6) | (ja[k] >> 12);
            unsigned slot = atomicAdd(&h[bk], 1u);
            unsigned packed = (unsigned)(ia[k] & 4095) | ((unsigned)(ja[k] & 4095) << 16);
            sorted[slot] = packed;
        }
    }
}

// ---------- Pass D: per-bucket compute, positions in LDS ----------
__global__ __launch_bounds__(1024) void bucket_compute_kernel(
    const float* __restrict__ x,
    const float* __restrict__ eps_p,
    const float* __restrict__ sig_p,
    const float* __restrict__ box_p,
    const unsigned* __restrict__ sorted,
    const unsigned* __restrict__ start,
    double* __restrict__ partials)
{
    extern __shared__ float sm[];           // 6 * 4096 floats = 96 KB
    const int b  = blockIdx.x;
    const int bi = b >> 6;
    const int bj = b & 63;

    // fill i-slice (sm[0..3*SLICE)) and j-slice (sm[3*SLICE..6*SLICE)), SoA
    {
        const float4* a4 = (const float4*)(x + (size_t)bi * SLICE * 3);
        const float4* b4 = (const float4*)(x + (size_t)bj * SLICE * 3);
        for (int k = threadIdx.x; k < (SLICE * 3) / 4; k += 1024) {
            float4 va = a4[k];
            float4 vb = b4[k];
            int base = 4 * k;
#pragma unroll
            for (int c = 0; c < 4; ++c) {
                int flat = base + c;
                int p = flat / 3;
                int comp = flat - 3 * p;
                sm[comp * SLICE + p] = (&va.x)[c];
                sm[3 * SLICE + comp * SLICE + p] = (&vb.x)[c];
            }
        }
    }
    __syncthreads();

    const float eps  = eps_p[0];
    const float sig  = sig_p[0];
    const float sig2 = sig * sig;
    const float L0 = box_p[0], L1 = box_p[1], L2 = box_p[2];
    const float i0 = 1.0f / L0, i1 = 1.0f / L1, i2 = 1.0f / L2;

    const float* xi = sm;
    const float* yi = sm + SLICE;
    const float* zi = sm + 2 * SLICE;
    const float* xj = sm + 3 * SLICE;
    const float* yj = sm + 4 * SLICE;
    const float* zj = sm + 5 * SLICE;

    const int s0 = (int)start[b];
    const int s1 = (int)start[b + 1];

    float sum = 0.0f;
    for (int s = s0 + threadIdx.x; s < s1; s += 1024) {
        unsigned u = __builtin_nontemporal_load(sorted + s);
        int li = (int)(u & 0xFFFFu);
        int lj = (int)(u >> 16);
        float dx = xi[li] - xj[lj];
        float dy = yi[li] - yj[lj];
        float dz = zi[li] - zj[lj];
        dx -= L0 * rintf(dx * i0);     // jnp.round == RNE == rintf
        dy -= L1 * rintf(dy * i1);
        dz -= L2 * rintf(dz * i2);
        const float r2 = dx * dx + dy * dy + dz * dz;
        const float s2 = sig2 / r2;
        const float s6 = s2 * s2 * s2;
        sum += s6 * s6 - s6;
    }
    double dsum = (double)(4.0f * eps * sum);

#pragma unroll
    for (int off = 32; off > 0; off >>= 1)
        dsum += __shfl_down(dsum, off, 64);

    __syncthreads();                        // done with sm as float
    double* red = (double*)sm;
    if ((threadIdx.x & 63) == 0) red[threadIdx.x >> 6] = dsum;
    __syncthreads();
    if (threadIdx.x == 0) {
        double t = 0.0;
        for (int w = 0; w < 16; ++w) t += red[w];
        partials[b] = t;
    }
}

// ---------- Pass E: final reduce ----------
__global__ __launch_bounds__(1024) void final_kernel(
    const double* __restrict__ partials, float* __restrict__ out)
{
    double s = 0.0;
    for (int i = threadIdx.x; i < NB; i += 1024) s += partials[i];
#pragma unroll
    for (int off = 32; off > 0; off >>= 1)
        s += __shfl_down(s, off, 64);
    __shared__ double red[16];
    if ((threadIdx.x & 63) == 0) red[threadIdx.x >> 6] = s;
    __syncthreads();
    if (threadIdx.x == 0) {
        double t = 0.0;
        for (int w = 0; w < 16; ++w) t += red[w];
        out[0] = (float)t;
    }
}

// ---------- Fallback (R3, proven 90us): aligned float4 gather ----------
__global__ __launch_bounds__(256) void repack_kernel(
    const float* __restrict__ x, float* __restrict__ xp, int n3)
{
    int t = blockIdx.x * 256 + threadIdx.x;
    if (t < n3) {
        float v = x[t];
        int p = t / 3;
        int c = t - 3 * p;
        xp[4 * p + c] = v;
    }
}

__global__ __launch_bounds__(256) void lj_pairs4_kernel(
    const float4* __restrict__ xp,
    const float* __restrict__ eps_p,
    const float* __restrict__ sig_p,
    const float* __restrict__ box_p,
    const vint4* __restrict__ idx_i4,
    const vint4* __restrict__ idx_j4,
    double*      __restrict__ partial)
{
    const int t = blockIdx.x * blockDim.x + threadIdx.x;
    const float eps  = eps_p[0];
    const float sig  = sig_p[0];
    const float sig2 = sig * sig;
    const float L0 = box_p[0], L1 = box_p[1], L2 = box_p[2];
    const float i0 = 1.0f / L0, i1 = 1.0f / L1, i2 = 1.0f / L2;

    const vint4 ii = __builtin_nontemporal_load(idx_i4 + t);
    const vint4 jj = __builtin_nontemporal_load(idx_j4 + t);
    const int ia[4] = {ii.x, ii.y, ii.z, ii.w};
    const int ja[4] = {jj.x, jj.y, jj.z, jj.w};

    float sum = 0.0f;
#pragma unroll
    for (int k = 0; k < 4; ++k) {
        const float4 pi = xp[ia[k]];
        const float4 pj = xp[ja[k]];
        float dx = pi.x - pj.x;
        float dy = pi.y - pj.y;
        float dz = pi.z - pj.z;
        dx -= L0 * rintf(dx * i0);
        dy -= L1 * rintf(dy * i1);
        dz -= L2 * rintf(dz * i2);
        const float r2 = dx * dx + dy * dy + dz * dz;
        const float s2 = sig2 / r2;
        const float s6 = s2 * s2 * s2;
        sum += s6 * s6 - s6;
    }
    double dsum = (double)(4.0f * eps * sum);
#pragma unroll
    for (int off = 32; off > 0; off >>= 1)
        dsum += __shfl_down(dsum, off, 64);
    __shared__ double wsum[4];
    if ((threadIdx.x & 63) == 0) wsum[threadIdx.x >> 6] = dsum;
    __syncthreads();
    if (threadIdx.x == 0)
        partial[blockIdx.x] = wsum[0] + wsum[1] + wsum[2] + wsum[3];
}

__global__ __launch_bounds__(256) void reduce_kernel(
    const double* __restrict__ partial, int n, float* __restrict__ out)
{
    double s = 0.0;
    for (int i = threadIdx.x; i < n; i += 256)
        s += partial[i];
#pragma unroll
    for (int off = 32; off > 0; off >>= 1)
        s += __shfl_down(s, off, 64);
    __shared__ double wsum[4];
    if ((threadIdx.x & 63) == 0) wsum[threadIdx.x >> 6] = s;
    __syncthreads();
    if (threadIdx.x == 0)
        out[0] = (float)(wsum[0] + wsum[1] + wsum[2] + wsum[3]);
}

extern "C" void kernel_launch(void* const* d_in, const int* in_sizes, int n_in,
                              void* d_out, int out_size, void* d_ws, size_t ws_size,
                              hipStream_t stream) {
    const float* x     = (const float*)d_in[0];
    const float* eps   = (const float*)d_in[1];
    const float* sigma = (const float*)d_in[2];
    const float* box   = (const float*)d_in[3];
    const vint4* ii    = (const vint4*)d_in[4];
    const vint4* jj    = (const vint4*)d_in[5];
    float* out = (float*)d_out;

    const int n_pairs = in_sizes[4];
    const int n_part  = in_sizes[0] / 3;

    // ws layout for fast path
    const size_t OFF_SORTED  = 0;                         // n_pairs * 4 B
    const size_t OFF_COUNT   = (size_t)n_pairs * 4;       // NB * 4
    const size_t OFF_START   = OFF_COUNT + NB * 4;        // (NB+1)*4 (+pad)
    const size_t OFF_CURSOR  = OFF_START + (NB + 64) * 4; // NB * 4
    const size_t OFF_PART    = OFF_CURSOR + NB * 4;       // NB * 8
    const size_t NEED        = OFF_PART + NB * 8;

    bool fast = (n_part == 262144) && (n_pairs == 8388608) && (ws_size >= NEED);
    if (fast) {
        hipError_t e = hipFuncSetAttribute(
            (const void*)bucket_compute_kernel,
            hipFuncAttributeMaxDynamicSharedMemorySize, 6 * SLICE * 4);
        if (e != hipSuccess) fast = false;
    }

    if (fast) {
        unsigned* sorted  = (unsigned*)((char*)d_ws + OFF_SORTED);
        unsigned* count   = (unsigned*)((char*)d_ws + OFF_COUNT);
        unsigned* start   = (unsigned*)((char*)d_ws + OFF_START);
        unsigned* cursor  = (unsigned*)((char*)d_ws + OFF_CURSOR);
        double*   partials= (double*)  ((char*)d_ws + OFF_PART);
        const int n4 = n_pairs / 4;

        hipMemsetAsync(count, 0, NB * 4, stream);
        hist_kernel<<<SB, ST, 0, stream>>>(ii, jj, count, n4);
        scan_kernel<<<1, ST, 0, stream>>>(count, start, cursor);
        scatter_kernel<<<SB, ST, 0, stream>>>(ii, jj, cursor, sorted, n4);
        bucket_compute_kernel<<<NB, 1024, 6 * SLICE * 4, stream>>>(
            x, eps, sigma, box, sorted, start, partials);
        final_kernel<<<1, 1024, 0, stream>>>(partials, out);
        return;
    }

    // fallback: R3 path
    const int block = 256;
    const int grid = (n_pairs / 4) / block;
    const size_t packed_bytes = (size_t)n_part * 16;
    float4* xp = (float4*)d_ws;
    double* partial = (double*)((char*)d_ws + packed_bytes);
    const int n3 = n_part * 3;
    repack_kernel<<<(n3 + block - 1) / block, block, 0, stream>>>(x, (float*)xp, n3);
    lj_pairs4_kernel<<<grid, block, 0, stream>>>(xp, eps, sigma, box, ii, jj, partial);
    reduce_kernel<<<1, block, 0, stream>>>(partial, grid, out);
}